// Round 7
// baseline (161.445 us; speedup 1.0000x reference)
//
#include <hip/hip_runtime.h>

// B=262144 x C=101 fp32 -> 3 scalars.
//
// R7: maximize memory-level parallelism. R2/R4/R5/R6 (four unrelated
// structures) all pin at ~2.4 TB/s effective read; occupancy, WG count,
// barriers, staging mechanism, VALU all excluded by experiment. Surviving
// theory: the harness's 423MB d_ws poison-fill + 212MB d_in restore thrash
// the 256MB LLC every iteration, and the fill's dirty-writeback drain to HBM
// bleeds into our kernel's window -> our reads share the controller with
// ~150MB of drain. Only kernel-side lever: never let the controller see an
// idle gap from us. So: R6's validated compute body (absmax 0), plus
//  - register double-buffer: group i+1's 7 loads + target issued BEFORE
//    computing group i (loads in flight across the whole shuffle chain),
//  - 2048 blocks x 256 thr (8192 waves, exactly 8 groups each, up to
//    32 waves/CU resident) for more concurrent load streams.

#define NC 101
#define LAMBDA_W 1000.0
#define NBLK 2048

__device__ __forceinline__ void load_group(const float* __restrict__ x,
                                           const int* __restrict__ tgt,
                                           int g, int team, int s,
                                           float e[7], int& t)
{
    const int row = g * 4 + team;
    const float* __restrict__ xr = x + (size_t)row * NC;
#pragma unroll
    for (int k = 0; k < 7; ++k) {
        const int j = s + 16 * k;
        e[k] = (j < NC) ? xr[j] : 0.f;
    }
    t = tgt[row];
}

__device__ __forceinline__ void compute_group(const float ein[7], int t,
                                              int lane, int s,
                                              float& conc, float& pens)
{
    // exp; force 0 (not exp(0)=1) on padded slots
    float e[7];
#pragma unroll
    for (int k = 0; k < 7; ++k) {
        const int j = s + 16 * k;
        float ee = __expf(ein[k]);
        e[k] = (j < NC) ? ee : 0.f;
    }

    // moments
    float S = 0.f, W = 0.f, Q = 0.f;
#pragma unroll
    for (int k = 0; k < 7; ++k) {
        const float fj = (float)(s + 16 * k);
        S += e[k];
        W = fmaf(e[k], fj, W);
        Q = fmaf(e[k], fj * fj, Q);
    }

    // penalty: pen = sum_j max(e_j - e_{j+1}, 0) - e_t, e_{>=101} = 0
    float pen = 0.f;
#pragma unroll
    for (int k = 0; k < 7; ++k) {
        float n1 = __shfl_down(e[k], 1);                 // s<15: e_{j+1}
        float nx = (k < 6) ? __shfl(e[k + 1], lane & 48) // team-base e at k+1
                           : 0.f;
        float en = (s == 15) ? nx : n1;
        float d  = e[k] - en;
        pen += fmaxf(d, 0.f);
        const int j = s + 16 * k;
        pen -= (j == t) ? e[k] : 0.f;
    }

    // 16-lane team reduce (xor folds stay in team)
#pragma unroll
    for (int off = 1; off < 16; off <<= 1) {
        S   += __shfl_xor(S, off);
        W   += __shfl_xor(W, off);
        Q   += __shfl_xor(Q, off);
        pen += __shfl_xor(pen, off);
    }

    if (s == 0) {
        float pred = W / S;
        float var  = fmaxf(fmaf(-pred, pred, Q / S), 1e-6f);
        float err  = pred - (float)t;
        conc += 0.5f * __logf(var) + err * err / (2.0f * var);
        pens += pen / S;
    }
}

__global__ __launch_bounds__(256)
void ucl_stream_kernel(const float* __restrict__ x,
                       const int* __restrict__ tgt,
                       float2* __restrict__ partial,
                       int ngroups)              // B/4
{
    const int tid  = threadIdx.x;
    const int lane = tid & 63;
    const int s    = lane & 15;
    const int team = lane >> 4;
    const int gwave  = blockIdx.x * 4 + (tid >> 6);
    const int nwaves = gridDim.x * 4;

    float conc = 0.f, pens = 0.f;

    float eA[7], eB[7];
    int tA = 0, tB = 0;

    int g = gwave;
    bool haveA = (g < ngroups);
    if (haveA)
        load_group(x, tgt, g, team, s, eA, tA);

    while (haveA) {
        const int gB = g + nwaves;
        const bool haveB = (gB < ngroups);
        if (haveB)
            load_group(x, tgt, gB, team, s, eB, tB);   // in flight across computeA
        compute_group(eA, tA, lane, s, conc, pens);
        if (!haveB) break;

        const int gA2 = gB + nwaves;
        haveA = (gA2 < ngroups);
        if (haveA)
            load_group(x, tgt, gA2, team, s, eA, tA);  // in flight across computeB
        compute_group(eB, tB, lane, s, conc, pens);
        g = gA2;
    }

    // wave reduce (row results live at lanes 0,16,32,48)
    conc += __shfl_down(conc, 16);
    pens += __shfl_down(pens, 16);
    conc += __shfl_down(conc, 32);
    pens += __shfl_down(pens, 32);

    __shared__ float red[8];
    if (lane == 0) {
        red[(tid >> 6) * 2 + 0] = conc;
        red[(tid >> 6) * 2 + 1] = pens;
    }
    __syncthreads();
    if (tid == 0)
        partial[blockIdx.x] = make_float2(red[0] + red[2] + red[4] + red[6],
                                          red[1] + red[3] + red[5] + red[7]);
}

__global__ __launch_bounds__(256)
void ucl_finalize(const float2* __restrict__ partial,
                  float* __restrict__ out,
                  int nblocks, double invB)
{
    const int tid = threadIdx.x;
    double c = 0.0, p = 0.0;
    for (int i = tid; i < nblocks; i += 256) {
        float2 v = partial[i];
        c += (double)v.x;
        p += (double)v.y;
    }
#pragma unroll
    for (int off = 32; off > 0; off >>= 1) {
        c += __shfl_down(c, off);
        p += __shfl_down(p, off);
    }
    __shared__ double sm[8];
    if ((tid & 63) == 0) { sm[(tid >> 6) * 2] = c; sm[(tid >> 6) * 2 + 1] = p; }
    __syncthreads();
    if (tid == 0) {
        double C = (sm[0] + sm[2] + sm[4] + sm[6]) * invB;
        double P = (sm[1] + sm[3] + sm[5] + sm[7]) * invB * LAMBDA_W;
        out[0] = (float)(C + P);
        out[1] = (float)C;
        out[2] = (float)P;
    }
}

extern "C" void kernel_launch(void* const* d_in, const int* in_sizes, int n_in,
                              void* d_out, int out_size, void* d_ws, size_t ws_size,
                              hipStream_t stream)
{
    const float* x   = (const float*)d_in[0];
    const int*   tgt = (const int*)d_in[1];
    float* out = (float*)d_out;
    float2* partial = (float2*)d_ws;

    const int B = in_sizes[1];        // 262144
    const int ngroups = B / 4;        // 65536
    const int blocks = NBLK;          // 2048 -> 8192 waves, exactly 8 groups each

    hipLaunchKernelGGL(ucl_stream_kernel, dim3(blocks), dim3(256), 0, stream,
                       x, tgt, partial, ngroups);
    hipLaunchKernelGGL(ucl_finalize, dim3(1), dim3(256), 0, stream,
                       partial, out, blocks, 1.0 / (double)B);
}

// Round 8
// 155.539 us; speedup vs baseline: 1.0380x; 1.0380x over previous
//
#include <hip/hip_runtime.h>

// B=262144 x C=101 fp32 -> 3 scalars.
//
// R8 = R6 verbatim (best measured: 153.7us bench). R7's MLP variant regressed
// to 161.4; restoring the best kernel and confirming reproducibility of the
// plateau. Structural ceiling evidence (R2/R4/R5/R6/R7, five orthogonal
// structures): in-kernel read rate pins at ~2.4-2.5 TB/s regardless of
// occupancy (2-32 waves/CU), WG count (683-2048), access pattern (scalar /
// float4 / global_load_lds), barriers or none; VALUBusy <=12%, conflicts 0.
// Bench = ~111us harness reset (423MB 0xAA fill @86% HBM peak + 212MB d_in
// restore) + ~42us kernel.
//
// Kernel: wave = 4 teams x 16 lanes; team owns one row; lane s holds
// j = s+16k, k=0..6. e_j := 0 for j>=101 =>
//   pen = sum_j max(e_j - e_{j+1}, 0) - e_t   (telescoped identity, absmax 0)
// Adjacent diffs via __shfl_down(1) + team-base seam shuffle; moments via
// 4 xor-shuffles (width 16). No LDS tiles, no barriers in hot loop.

#define NC 101
#define LAMBDA_W 1000.0

__global__ __launch_bounds__(256)
void ucl_stream_kernel(const float* __restrict__ x,
                       const int* __restrict__ tgt,
                       float2* __restrict__ partial,
                       int ngroups)              // B/4 row-groups
{
    const int tid  = threadIdx.x;
    const int lane = tid & 63;
    const int s    = lane & 15;                  // slot within team
    const int gwave  = blockIdx.x * 4 + (tid >> 6);
    const int nwaves = gridDim.x * 4;

    float conc = 0.f, pens = 0.f;

    for (int g = gwave; g < ngroups; g += nwaves) {
        const int row = g * 4 + (lane >> 4);     // team's row
        const float* __restrict__ xr = x + (size_t)row * NC;
        const int t = tgt[row];                  // broadcast within team

        // ---- hoisted predicated loads, j = s + 16k ----
        float e[7];
#pragma unroll
        for (int k = 0; k < 7; ++k) {
            const int j = s + 16 * k;
            e[k] = (j < NC) ? xr[j] : 0.f;
        }
        // exp; force 0 (not exp(0)=1) on padded lanes
#pragma unroll
        for (int k = 0; k < 7; ++k) {
            const int j = s + 16 * k;
            float ee = __expf(e[k]);
            e[k] = (j < NC) ? ee : 0.f;
        }

        // ---- moments ----
        float S = 0.f, W = 0.f, Q = 0.f;
#pragma unroll
        for (int k = 0; k < 7; ++k) {
            const float fj = (float)(s + 16 * k);
            S += e[k];
            W = fmaf(e[k], fj, W);
            Q = fmaf(e[k], fj * fj, Q);
        }

        // ---- penalty: d_j = e_j - e_{j+1} (e_{101..} = 0) ----
        float pen = 0.f;
#pragma unroll
        for (int k = 0; k < 7; ++k) {
            float n1 = __shfl_down(e[k], 1);                 // s<15: e_{j+1}
            float nx = (k < 6) ? __shfl(e[k + 1], lane & 48) // own team base, k+1
                               : 0.f;
            float en = (s == 15) ? nx : n1;
            float d  = e[k] - en;
            pen += fmaxf(d, 0.f);
            const int j = s + 16 * k;
            pen -= (j == t) ? e[k] : 0.f;                    // -e_t by owner
        }

        // ---- team reduce (xor folds stay within 16-lane team) ----
#pragma unroll
        for (int off = 1; off < 16; off <<= 1) {
            S   += __shfl_xor(S, off);
            W   += __shfl_xor(W, off);
            Q   += __shfl_xor(Q, off);
            pen += __shfl_xor(pen, off);
        }

        if (s == 0) {                            // one lane per row finalizes
            float pred = W / S;
            float var  = fmaxf(fmaf(-pred, pred, Q / S), 1e-6f);
            float err  = pred - (float)t;
            conc += 0.5f * __logf(var) + err * err / (2.0f * var);
            pens += pen / S;
        }
    }

    // ---- wave reduce (values at lanes 0,16,32,48) ----
    conc += __shfl_down(conc, 16);
    pens += __shfl_down(pens, 16);
    conc += __shfl_down(conc, 32);
    pens += __shfl_down(pens, 32);

    __shared__ float red[8];
    if (lane == 0) {
        red[(tid >> 6) * 2 + 0] = conc;
        red[(tid >> 6) * 2 + 1] = pens;
    }
    __syncthreads();
    if (tid == 0)
        partial[blockIdx.x] = make_float2(red[0] + red[2] + red[4] + red[6],
                                          red[1] + red[3] + red[5] + red[7]);
}

__global__ __launch_bounds__(256)
void ucl_finalize(const float2* __restrict__ partial,
                  float* __restrict__ out,
                  int nblocks, double invB)
{
    const int tid = threadIdx.x;
    double c = 0.0, p = 0.0;
    for (int i = tid; i < nblocks; i += 256) {
        float2 v = partial[i];
        c += (double)v.x;
        p += (double)v.y;
    }
#pragma unroll
    for (int off = 32; off > 0; off >>= 1) {
        c += __shfl_down(c, off);
        p += __shfl_down(p, off);
    }
    __shared__ double sm[8];
    if ((tid & 63) == 0) { sm[(tid >> 6) * 2] = c; sm[(tid >> 6) * 2 + 1] = p; }
    __syncthreads();
    if (tid == 0) {
        double C = (sm[0] + sm[2] + sm[4] + sm[6]) * invB;
        double P = (sm[1] + sm[3] + sm[5] + sm[7]) * invB * LAMBDA_W;
        out[0] = (float)(C + P);
        out[1] = (float)C;
        out[2] = (float)P;
    }
}

extern "C" void kernel_launch(void* const* d_in, const int* in_sizes, int n_in,
                              void* d_out, int out_size, void* d_ws, size_t ws_size,
                              hipStream_t stream)
{
    const float* x   = (const float*)d_in[0];
    const int*   tgt = (const int*)d_in[1];
    float* out = (float*)d_out;
    float2* partial = (float2*)d_ws;

    const int B = in_sizes[1];        // 262144
    const int ngroups = B / 4;        // 65536
    const int blocks = 1024;

    hipLaunchKernelGGL(ucl_stream_kernel, dim3(blocks), dim3(256), 0, stream,
                       x, tgt, partial, ngroups);
    hipLaunchKernelGGL(ucl_finalize, dim3(1), dim3(256), 0, stream,
                       partial, out, blocks, 1.0 / (double)B);
}